// Round 6
// baseline (639.499 us; speedup 1.0000x reference)
//
#include <hip/hip_runtime.h>
#include <cstddef>

namespace {
constexpr int Z    = 4;
constexpr int N    = 256;
constexpr int CIN  = 32;
constexpr int COUT = 32;
constexpr int HID  = 64;
constexpr int OC   = COUT * CIN;  // 1024
}

typedef float f4 __attribute__((ext_vector_type(4)));

// ---------------------------------------------------------------------------
// Kernel T: W2T[j][i][h] = W2[h][i*32+j].  256 KB once per launch.
// Reads coalesced f4; 4 B scatter stores are assembled into full lines in L2
// (every line of W2T is written completely).
// ---------------------------------------------------------------------------
__global__ __launch_bounds__(256) void transpose_W2(
    const float* __restrict__ W2, float* __restrict__ W2T)
{
    const int h = blockIdx.x;            // 0..63
    const int t = threadIdx.x;           // 0..255
    const f4 v = reinterpret_cast<const f4*>(W2 + (size_t)h * OC)[t];
    const int i  = t >> 3;
    const int j0 = (t & 7) * 4;
    W2T[((size_t)(j0 + 0) * COUT + i) * HID + h] = v.x;
    W2T[((size_t)(j0 + 1) * COUT + i) * HID + h] = v.y;
    W2T[((size_t)(j0 + 2) * COUT + i) * HID + h] = v.z;
    W2T[((size_t)(j0 + 3) * COUT + i) * HID + h] = v.w;
}

// ---------------------------------------------------------------------------
// Kernel A: one block per b.
//   M[z][b][i][h] = sum_j f[z,b,j] * W2T[j][i][h]
//   bf[z][b][i]   = sum_j b2[i*32+j] * f[z,b,j]
// W2T reads are PERFECTLY coalesced: per wave-load, lanes (i_l 0..3, h4 0..15)
// cover a contiguous 1 KB run (R5's kernel A had lane-stride-128B gathers —
// 64 line-probes per instruction, the suspected ~70 us tail).
// Features go through LDS (wave-uniform broadcast reads, free).
// ---------------------------------------------------------------------------
__global__ __launch_bounds__(256) void build_M(
    const float* __restrict__ features,
    const float* __restrict__ W2T,
    const float* __restrict__ b2,
    float* __restrict__ Mws,
    float* __restrict__ bfws)
{
    __shared__ __align__(16) float fl[4 * CIN];   // f[z][j]
    const int b = blockIdx.x;        // 0..255
    const int t = threadIdx.x;

    if (t < 128)
        fl[t] = features[((size_t)(t >> 5) * N + b) * CIN + (t & 31)];
    __syncthreads();

    const int h4 = t & 15;           // h-quad
    const int il = t >> 4;           // 0..15
#pragma unroll
    for (int half = 0; half < 2; ++half) {
        const int i = il + 16 * half;
        f4 a0 = 0.f, a1 = 0.f, a2 = 0.f, a3 = 0.f;
#pragma unroll 8
        for (int j = 0; j < 32; ++j) {
            const f4 w = reinterpret_cast<const f4*>(W2T)[(size_t)j * 512 + i * 16 + h4];
            a0 += fl[j]      * w;
            a1 += fl[32 + j] * w;
            a2 += fl[64 + j] * w;
            a3 += fl[96 + j] * w;
        }
        reinterpret_cast<f4*>(Mws)[((size_t)(0 * N + b) * COUT + i) * 16 + h4] = a0;
        reinterpret_cast<f4*>(Mws)[((size_t)(1 * N + b) * COUT + i) * 16 + h4] = a1;
        reinterpret_cast<f4*>(Mws)[((size_t)(2 * N + b) * COUT + i) * 16 + h4] = a2;
        reinterpret_cast<f4*>(Mws)[((size_t)(3 * N + b) * COUT + i) * 16 + h4] = a3;
    }

    if (t < 128) {   // bf: tiny, b2 is 4 KB L2-hot
        const int z = t >> 5, ii = t & 31;
        float v = 0.f;
#pragma unroll
        for (int q = 0; q < 8; ++q) {
            const f4 bb = *reinterpret_cast<const f4*>(b2 + ii * CIN + q * 4);
            const f4 f  = *reinterpret_cast<const f4*>(&fl[z * 32 + q * 4]);
            v += bb.x * f.x + bb.y * f.y + bb.z * f.z + bb.w * f.w;
        }
        bfws[((size_t)z * N + b) * COUT + ii] = v;
    }
}

// ---------------------------------------------------------------------------
// Kernel B: one block per (z,b).  H in REGISTERS (recomputed per k-chunk from
// dx/dy/dz + s_loaded W1), killing the 68 KB Hs buffer: LDS 77.5 -> 29.9 KB,
// occupancy 2 -> 4 blocks/CU (all 1024 blocks resident).  W1/b1 read with
// wave-uniform addresses -> s_load, zero LDS/VALU cost.
// Thread tile 8a x 4i; live set ~91 VGPRs so __launch_bounds__(256,4)'s
// 128-VGPR cap is spill-free (R2's trap was a ~140-reg live set at 64 cap).
// ---------------------------------------------------------------------------
__global__ __launch_bounds__(256, 4) void pair_contract(
    const float* __restrict__ geometry,
    const float* __restrict__ W1,
    const float* __restrict__ b1,
    const float* __restrict__ Mws,
    const float* __restrict__ bfws,
    float* __restrict__ out)
{
    __shared__ __align__(16) float Ml[COUT * HID];   // 8 KB  M[i][h]
    __shared__ __align__(16) float stage[128 * 36];  // 18 KB epilogue transpose
    __shared__ __align__(16) float geo[N * 3];       // 3 KB
    __shared__ float bfl[COUT];

    const int blk = blockIdx.x;   // 1024; XCD = blk%8 = b%8, matches build_M
    const int z = blk >> 8;
    const int b = blk & 255;
    const int t = threadIdx.x;

    if (t < 192)
        reinterpret_cast<f4*>(geo)[t] =
            reinterpret_cast<const f4*>(geometry + (size_t)z * N * 3)[t];
    if (t < COUT) bfl[t] = bfws[((size_t)z * N + b) * COUT + t];
    {
        const f4* Ms = reinterpret_cast<const f4*>(Mws + (size_t)(z * N + b) * (COUT * HID));
        f4* Ml4 = reinterpret_cast<f4*>(Ml);
        Ml4[t]       = Ms[t];
        Ml4[t + 256] = Ms[t + 256];
    }
    // wave-uniform -> s_load
    const float gbx = geometry[((size_t)z * N + b) * 3 + 0];
    const float gby = geometry[((size_t)z * N + b) * 3 + 1];
    const float gbz = geometry[((size_t)z * N + b) * 3 + 2];
    __syncthreads();

    const int a_thr = t & 31;
    const int i_thr = t >> 5;     // 0..7
    float dx[8], dy[8], dz[8];
#pragma unroll
    for (int u = 0; u < 8; ++u) {
        const int a = a_thr + 32 * u;
        dx[u] = gbx - geo[a * 3 + 0];
        dy[u] = gby - geo[a * 3 + 1];
        dz[u] = gbz - geo[a * 3 + 2];
    }

    float acc[8][4];
#pragma unroll
    for (int u = 0; u < 8; ++u)
#pragma unroll
        for (int v = 0; v < 4; ++v) acc[u][v] = bfl[i_thr * 4 + v];

#pragma unroll
    for (int k4 = 0; k4 < 16; ++k4) {
        // wave-uniform W1/b1 quads -> s_load_dwordx4 (no LDS traffic)
        const f4 wx = *reinterpret_cast<const f4*>(W1 + k4 * 4);
        const f4 wy = *reinterpret_cast<const f4*>(W1 + HID + k4 * 4);
        const f4 wz = *reinterpret_cast<const f4*>(W1 + 2 * HID + k4 * 4);
        const f4 bb = *reinterpret_cast<const f4*>(b1 + k4 * 4);
        f4 m[4];
#pragma unroll
        for (int v = 0; v < 4; ++v)
            m[v] = *reinterpret_cast<const f4*>(&Ml[(i_thr * 4 + v) * HID + k4 * 4]);
#pragma unroll
        for (int u = 0; u < 8; ++u) {
            f4 h;
            h.x = fmaxf(fmaf(dx[u], wx.x, fmaf(dy[u], wy.x, fmaf(dz[u], wz.x, bb.x))), 0.f);
            h.y = fmaxf(fmaf(dx[u], wx.y, fmaf(dy[u], wy.y, fmaf(dz[u], wz.y, bb.y))), 0.f);
            h.z = fmaxf(fmaf(dx[u], wx.z, fmaf(dy[u], wy.z, fmaf(dz[u], wz.z, bb.z))), 0.f);
            h.w = fmaxf(fmaf(dx[u], wx.w, fmaf(dy[u], wy.w, fmaf(dz[u], wz.w, bb.w))), 0.f);
#pragma unroll
            for (int v = 0; v < 4; ++v)
                acc[u][v] += h.x * m[v].x + h.y * m[v].y + h.z * m[v].z + h.w * m[v].w;
        }
    }

    // epilogue: transpose through LDS in two 128-a halves, coalesced stores
    const size_t out_zb = ((size_t)z * N) * N + b;
#pragma unroll
    for (int half = 0; half < 2; ++half) {
#pragma unroll
        for (int u = 0; u < 4; ++u) {
            const int uu = half * 4 + u;
            f4 o;
            o.x = acc[uu][0]; o.y = acc[uu][1]; o.z = acc[uu][2]; o.w = acc[uu][3];
            *reinterpret_cast<f4*>(&stage[(a_thr + 32 * u) * 36 + i_thr * 4]) = o;
        }
        __syncthreads();
#pragma unroll
        for (int r = 0; r < 4; ++r) {
            const int c     = r * 256 + t;      // 0..1023
            const int a_loc = c >> 3;           // 0..127
            const int i4    = c & 7;
            const int a     = half * 128 + a_loc;
            const f4 val = *reinterpret_cast<const f4*>(&stage[a_loc * 36 + i4 * 4]);
            *reinterpret_cast<f4*>(&out[(out_zb + (size_t)a * N) * COUT + i4 * 4]) = val;
        }
        __syncthreads();
    }
}

extern "C" void kernel_launch(void* const* d_in, const int* in_sizes, int n_in,
                              void* d_out, int out_size, void* d_ws, size_t ws_size,
                              hipStream_t stream) {
    const float* features = (const float*)d_in[0];
    const float* geometry = (const float*)d_in[1];
    const float* W1 = (const float*)d_in[2];
    const float* b1 = (const float*)d_in[3];
    const float* W2 = (const float*)d_in[4];
    const float* b2 = (const float*)d_in[5];
    float* out = (float*)d_out;

    float* W2T  = (float*)d_ws;                       // 65,536 floats (256 KB)
    float* Mws  = W2T + (size_t)CIN * COUT * HID;     // 2,097,152 floats (8 MB)
    float* bfws = Mws + (size_t)Z * N * COUT * HID;   // 32,768 floats

    transpose_W2<<<HID, 256, 0, stream>>>(W2, W2T);
    build_M<<<N, 256, 0, stream>>>(features, W2T, b2, Mws, bfws);
    pair_contract<<<Z * N, 256, 0, stream>>>(geometry, W1, b1, Mws, bfws, out);
}